// Round 10
// baseline (477.583 us; speedup 1.0000x reference)
//
#include <hip/hip_runtime.h>

#define NW 12

typedef float f2 __attribute__((ext_vector_type(2)));

// data-movement source index for the 5-CNOT chain on 6 local bits
// (control bit k+1, target bit k, applied from high control to low)
__device__ constexpr int perm64c(int j) {
    j ^= (j >> 1) & 1;
    j ^= (j >> 1) & 2;
    j ^= (j >> 1) & 4;
    j ^= (j >> 1) & 8;
    j ^= (j >> 1) & 16;
    return j;
}

// parity of j bits 5..(5-k)  (prefix parity, compile-time after unroll)
__device__ constexpr int ppar(int j, int k) {
    int p = 0;
    for (int i = 0; i <= k; ++i) p ^= (j >> (5 - i)) & 1;
    return p;
}

__device__ __forceinline__ f2 sp(float x) { f2 v; v.x = x; v.y = x; return v; }

// element access into packed state (j compile-time after unroll)
__device__ __forceinline__ float elv(const f2* A, int j) {
    return (j & 1) ? A[j >> 1].y : A[j >> 1].x;
}

// ---------------- RX butterfly on packed-pair distance PM (wire mask M=2*PM) ----
// Pure element-wise packed math -> v_pk_mul/v_pk_fma on gfx950.
template<int PM>
__device__ __forceinline__ void rx_pk(f2* R, f2* I, f2 c, f2 s) {
    #pragma unroll
    for (int k0 = 0; k0 < 32; ++k0) {
        if (k0 & PM) continue;
        const int k1 = k0 | PM;
        const f2 ar = R[k0], ai = I[k0], br = R[k1], bi = I[k1];
        R[k0] = c * ar + s * bi;
        I[k0] = c * ai - s * br;
        R[k1] = c * br + s * ai;
        I[k1] = c * bi - s * ar;
    }
}

// RX on the packed-internal bit (wire mask M=1): partner is the other f2 half.
__device__ __forceinline__ void rx_pk0(f2* R, f2* I, f2 c, f2 s) {
    #pragma unroll
    for (int k = 0; k < 32; ++k) {
        const f2 Rs = R[k].yx, Is = I[k].yx;   // swapped partner view
        R[k] = c * R[k] + s * Is;
        I[k] = c * I[k] - s * Rs;
    }
}

// 6 RX gates on the local bits; original mask order 32,16,8,4,2,1
__device__ __forceinline__ void rx_sweep(f2* R, f2* I, const float2* __restrict__ cs) {
    { const float2 q = cs[0]; rx_pk<16>(R, I, sp(q.x), sp(q.y)); }
    { const float2 q = cs[1]; rx_pk<8>(R, I, sp(q.x), sp(q.y)); }
    { const float2 q = cs[2]; rx_pk<4>(R, I, sp(q.x), sp(q.y)); }
    { const float2 q = cs[3]; rx_pk<2>(R, I, sp(q.x), sp(q.y)); }
    { const float2 q = cs[4]; rx_pk<1>(R, I, sp(q.x), sp(q.y)); }
    { const float2 q = cs[5]; rx_pk0(R, I, sp(q.x), sp(q.y)); }
}

// combined diagonal (6 RZs) in packed layout: z[k] = (zx(2k),zx(2k+1),zy(2k),zy(2k+1))
__device__ __forceinline__ void diag_pk(f2* R, f2* I, const float4* __restrict__ z) {
    #pragma unroll
    for (int k = 0; k < 32; ++k) {
        const float4 q = z[k];
        f2 zx; zx.x = q.x; zx.y = q.y;
        f2 zy; zy.x = q.z; zy.y = q.w;
        const f2 nr = R[k] * zx - I[k] * zy;
        const f2 ni = I[k] * zx + R[k] * zy;
        R[k] = nr; I[k] = ni;
    }
}

// compile-time permutation (register renames; pair->pair with optional half-swap)
__device__ __forceinline__ void perm_pk(f2* R, f2* I) {
    f2 tR[32], tI[32];
    #pragma unroll
    for (int k = 0; k < 32; ++k) {
        const int s0 = perm64c(2 * k);
        const int k2 = s0 >> 1;
        if (s0 & 1) { tR[k] = R[k2].yx; tI[k] = I[k2].yx; }
        else        { tR[k] = R[k2];    tI[k] = I[k2];    }
    }
    #pragma unroll
    for (int k = 0; k < 32; ++k) { R[k] = tR[k]; I[k] = tI[k]; }
}

// CNOT(5,6) in L2 layout: wire5 = packed-internal bit, wire6 = lane bit5
__device__ __forceinline__ void cnot56_L2(f2* R, f2* I) {
    #pragma unroll
    for (int k = 0; k < 32; ++k) {
        R[k].y = __shfl_xor(R[k].y, 32, 64);
        I[k].y = __shfl_xor(I[k].y, 32, 64);
    }
}

// CNOT(5,6) in L1 layout: wire5 = lane bit0, wire6 = packed-index bit4
__device__ __forceinline__ void cnot56_L1(f2* R, f2* I, int lane) {
    const bool c = (lane & 1) != 0;
    #pragma unroll
    for (int k = 0; k < 16; ++k) {
        const f2 a0 = R[k], a1 = R[k + 16], b0 = I[k], b1 = I[k + 16];
        R[k]      = c ? a1 : a0;  R[k + 16] = c ? a0 : a1;
        I[k]      = c ? b1 : b0;  I[k + 16] = c ? b0 : b1;
    }
}

// ---------------- in-wave 64x64 transpose via LDS (no barriers) ----------------
// logical (row R, col C) stored at byte R*256 + (((C>>2) ^ (R&15))<<4) + (C&3)*4
// read addr for row r, col=lane: rb ^ (((r&15)<<4) | (r<<8)),
// rb = ((lane>>2)<<4) | ((lane&3)<<2)
template<bool PRE, bool POST>
__device__ __forceinline__ void tpose(float* pl, f2* R, f2* I, const int lane, const int rb) {
    char* base = reinterpret_cast<char*>(pl);
    const int ls = lane & 15;
    const int wb = lane << 8;
    // ---- RE plane ----
    #pragma unroll
    for (int g = 0; g < 16; ++g) {
        float4 v;
        v.x = elv(R, PRE ? perm64c(4 * g + 0) : 4 * g + 0);
        v.y = elv(R, PRE ? perm64c(4 * g + 1) : 4 * g + 1);
        v.z = elv(R, PRE ? perm64c(4 * g + 2) : 4 * g + 2);
        v.w = elv(R, PRE ? perm64c(4 * g + 3) : 4 * g + 3);
        *reinterpret_cast<float4*>(base + wb + ((g ^ ls) << 4)) = v;
    }
    #pragma unroll
    for (int k = 0; k < 32; ++k) {
        const int r0 = POST ? perm64c(2 * k) : 2 * k;
        const int r1 = r0 ^ 1;               // perm64c(2k+1) == perm64c(2k)^1
        f2 nv;
        nv.x = *reinterpret_cast<const float*>(base + (rb ^ (((r0 & 15) << 4) | (r0 << 8))));
        nv.y = *reinterpret_cast<const float*>(base + (rb ^ (((r1 & 15) << 4) | (r1 << 8))));
        R[k] = nv;
    }
    // ---- IM plane (reuses buffer; per-wave DS ordering guarantees WAR safety) ----
    #pragma unroll
    for (int g = 0; g < 16; ++g) {
        float4 v;
        v.x = elv(I, PRE ? perm64c(4 * g + 0) : 4 * g + 0);
        v.y = elv(I, PRE ? perm64c(4 * g + 1) : 4 * g + 1);
        v.z = elv(I, PRE ? perm64c(4 * g + 2) : 4 * g + 2);
        v.w = elv(I, PRE ? perm64c(4 * g + 3) : 4 * g + 3);
        *reinterpret_cast<float4*>(base + wb + ((g ^ ls) << 4)) = v;
    }
    #pragma unroll
    for (int k = 0; k < 32; ++k) {
        const int r0 = POST ? perm64c(2 * k) : 2 * k;
        const int r1 = r0 ^ 1;
        f2 nv;
        nv.x = *reinterpret_cast<const float*>(base + (rb ^ (((r0 & 15) << 4) | (r0 << 8))));
        nv.y = *reinterpret_cast<const float*>(base + (rb ^ (((r1 & 15) << 4) | (r1 << 8))));
        I[k] = nv;
    }
}

// ---------------- precompute (batch-uniform gate constants) ----------------
__global__ void qr_pre(const float* __restrict__ params,
                       float2* __restrict__ tabcs,   // [8][6]
                       float* __restrict__ zpk)      // [6][32][4] = (zx0,zx1,zy0,zy1)
{
    const int t = threadIdx.x;
    if (t < 48) {
        const int h = t / 6, k = t - h * 6;
        const int l = h >> 1;
        const int base = (((h & 3) == 0) || ((h & 3) == 3)) ? 6 : 0;
        const float th = 0.5f * params[l * 12 + base + k];
        tabcs[t] = make_float2(cosf(th), sinf(th));
    }
    if (t < 384) {
        const int h = t >> 6, j = t & 63;
        const int l = h >> 1;
        const int base = (((h & 3) == 0) || ((h & 3) == 3)) ? 6 : 0;
        float pr = 1.f, pi = 0.f;
        for (int k = 0; k < 6; ++k) {
            const float th = 0.5f * params[l * 12 + base + k];
            const float c = cosf(th), s = sinf(th);
            const float ss = (j & (32 >> k)) ? s : -s;   // bit set -> e^{+i th/2}
            const float nr = pr * c - pi * ss;
            pi = pr * ss + pi * c;
            pr = nr;
        }
        float* q = zpk + (h * 32 + (j >> 1)) * 4;
        q[j & 1] = pr;
        q[2 + (j & 1)] = pi;
    }
}

// ---------------- main: 2 independent waves per block, 1 sample per wave ----
// Occupancy evidence: HW co-schedules ~3.5 blocks/CU when LDS permits
// (r1: 32K blocks -> 3.66; r7: 16K blocks -> 3.5), but a 64 KiB block drops
// to 1 block/CU (r8: 0.94 -> dur unchanged). So: pack 2 waves per block at
// 2x16 KiB = 32 KiB LDS -> LDS allows 5 blocks/CU, block-cap ~3.5-4 gives
// ~7-8 waves/CU, ~2x round-7 residency. No barriers; private LDS per wave.
// launch_bounds(128, 1): VGPR cap 512 (r6 lesson: tighter caps demote the
// state array to scratch -> GB-scale HBM traffic).
__global__ __launch_bounds__(128, 1) void qr_main(
    const float* __restrict__ inputs,
    const float2* __restrict__ tabcs,
    const float4* __restrict__ zpk,
    const float* __restrict__ head_w,
    const float* __restrict__ head_b,
    float* __restrict__ out)
{
    __shared__ __align__(16) float pl[8192];   // 32 KiB: 16 KiB per wave
    const int lane = threadIdx.x & 63;
    const int wv = threadIdx.x >> 6;
    const int b = blockIdx.x * 2 + wv;
    float* plw = pl + (wv << 12);

    // per-sample encoding angles
    float cy[12], sy[12];
    #pragma unroll
    for (int i = 0; i < 12; ++i) {
        __sincosf(0.5f * inputs[b * 12 + i], &sy[i], &cy[i]);
    }

    // product-state init in L1 (lane bits = wires 0-5, local bits = wires 6-11)
    float F = 1.f;
    #pragma unroll
    for (int i = 0; i < 6; ++i) F *= (lane & (32 >> i)) ? sy[i] : cy[i];

    // hi: wires 6,7,8 (packed-index bits 4..2); lop: wires 9,10 (bits 1..0) x wire 11 packed
    float hi[8];
    #pragma unroll
    for (int m = 0; m < 8; ++m)
        hi[m] = ((m & 4) ? sy[6] : cy[6]) * ((m & 2) ? sy[7] : cy[7]) * ((m & 1) ? sy[8] : cy[8]);
    f2 lop[4];
    #pragma unroll
    for (int m = 0; m < 4; ++m) {
        const float q = ((m & 2) ? sy[9] : cy[9]) * ((m & 1) ? sy[10] : cy[10]);
        lop[m].x = q * cy[11];
        lop[m].y = q * sy[11];
    }

    f2 R[32], I[32];
    #pragma unroll
    for (int k = 0; k < 32; ++k) {
        R[k] = sp(F * hi[k >> 2]) * lop[k & 3];
        I[k] = sp(0.f);
    }

    // transpose read-address base (bytes); per-row constants folded at compile time
    const int rb = (((lane >> 2) << 4) | ((lane & 3) << 2));

    // 8 half-layers; layout alternates L1/L2 via transposes
    #pragma unroll 1
    for (int h = 0; h < 8; ++h) {
        rx_sweep(R, I, tabcs + h * 6);
        if (h < 6) diag_pk(R, I, zpk + h * 32);

        if (h == 1 || h == 5) {
            perm_pk(R, I);           // CNOT(0,1)..(4,5) renames (L2)
            cnot56_L2(R, I);         // CNOT(5,6); chain(6..11) deferred
        } else if (h == 3) {
            cnot56_L1(R, I, lane);   // CNOT(5,6) in L1
            perm_pk(R, I);           // CNOT(6,7)..(10,11) renames (L1)
        } else if (h == 0 || h == 4) {
            tpose<false, false>(plw, R, I, lane, rb);
        } else if (h == 2) {
            tpose<true, true>(plw, R, I, lane, rb);   // pre: this layer's (0,1)..(4,5); post: deferred chain
        } else if (h == 6) {
            tpose<false, true>(plw, R, I, lane, rb);  // post: layer-2's deferred chain
        }
        // h == 7: done (layer-3 RZs + CNOT chain folded into measurement)
    }

    // measurement in L1; layer-3 CNOT chain -> prefix-parity signs
    float w[12];
    #pragma unroll
    for (int i = 0; i < 12; ++i) w[i] = head_w[i];

    float C = 0.f; int par = 0;
    #pragma unroll
    for (int i = 0; i < 6; ++i) {
        par ^= (lane >> (5 - i)) & 1;
        C += par ? -w[i] : w[i];
    }
    const float sg = par ? -1.f : 1.f;

    float phi = 0.f;
    #pragma unroll
    for (int j = 0; j < 64; ++j) {
        const float re = elv(R, j), im = elv(I, j);
        const float p = re * re + im * im;
        float D = 0.f;
        #pragma unroll
        for (int k = 0; k < 6; ++k) {
            D += ppar(j, k) ? -w[6 + k] : w[6 + k];
        }
        phi += (C + sg * D) * p;
    }

    #pragma unroll
    for (int m = 32; m; m >>= 1) phi += __shfl_xor(phi, m, 64);
    if (lane == 0) out[b] = phi + head_b[0];
}

extern "C" void kernel_launch(void* const* d_in, const int* in_sizes, int n_in,
                              void* d_out, int out_size, void* d_ws, size_t ws_size,
                              hipStream_t stream) {
    const float* inputs = (const float*)d_in[0];
    const float* params = (const float*)d_in[1];
    const float* head_w = (const float*)d_in[2];
    const float* head_b = (const float*)d_in[3];
    float* out = (float*)d_out;

    float2* tabcs = (float2*)d_ws;                 // 48 float2 = 384 B
    float*  zpk   = (float*)d_ws + 96;             // 6*32 float4 = 3072 B (16B-aligned: 384%16==0)

    const int batch = in_sizes[0] / NW;

    qr_pre<<<1, 384, 0, stream>>>(params, tabcs, zpk);
    qr_main<<<batch / 2, 128, 0, stream>>>(inputs, tabcs, (const float4*)zpk, head_w, head_b, out);
}

// Round 12
// 452.491 us; speedup vs baseline: 1.0555x; 1.0555x over previous
//
#include <hip/hip_runtime.h>

#define NW 12

typedef float f2 __attribute__((ext_vector_type(2)));

// data-movement source index for the 5-CNOT chain on 6 local bits
// (control bit k+1, target bit k, applied from high control to low)
__device__ constexpr int perm64c(int j) {
    j ^= (j >> 1) & 1;
    j ^= (j >> 1) & 2;
    j ^= (j >> 1) & 4;
    j ^= (j >> 1) & 8;
    j ^= (j >> 1) & 16;
    return j;
}

// parity of j bits 5..(5-k)  (prefix parity, compile-time after unroll)
__device__ constexpr int ppar(int j, int k) {
    int p = 0;
    for (int i = 0; i <= k; ++i) p ^= (j >> (5 - i)) & 1;
    return p;
}

__device__ __forceinline__ f2 sp(float x) { f2 v; v.x = x; v.y = x; return v; }

// element access into packed state (j compile-time after unroll)
__device__ __forceinline__ float elv(const f2* A, int j) {
    return (j & 1) ? A[j >> 1].y : A[j >> 1].x;
}

// ---------------- RX butterfly on packed-pair distance PM (wire mask M=2*PM) ----
// Pure element-wise packed math -> v_pk_mul/v_pk_fma on gfx950.
template<int PM>
__device__ __forceinline__ void rx_pk(f2* R, f2* I, f2 c, f2 s) {
    #pragma unroll
    for (int k0 = 0; k0 < 32; ++k0) {
        if (k0 & PM) continue;
        const int k1 = k0 | PM;
        const f2 ar = R[k0], ai = I[k0], br = R[k1], bi = I[k1];
        R[k0] = c * ar + s * bi;
        I[k0] = c * ai - s * br;
        R[k1] = c * br + s * ai;
        I[k1] = c * bi - s * ar;
    }
}

// RX on the packed-internal bit (wire mask M=1): partner is the other f2 half.
__device__ __forceinline__ void rx_pk0(f2* R, f2* I, f2 c, f2 s) {
    #pragma unroll
    for (int k = 0; k < 32; ++k) {
        const f2 Rs = R[k].yx, Is = I[k].yx;   // swapped partner view
        R[k] = c * R[k] + s * Is;
        I[k] = c * I[k] - s * Rs;
    }
}

// 6 RX gates on the local bits; original mask order 32,16,8,4,2,1
__device__ __forceinline__ void rx_sweep(f2* R, f2* I, const float2* __restrict__ cs) {
    { const float2 q = cs[0]; rx_pk<16>(R, I, sp(q.x), sp(q.y)); }
    { const float2 q = cs[1]; rx_pk<8>(R, I, sp(q.x), sp(q.y)); }
    { const float2 q = cs[2]; rx_pk<4>(R, I, sp(q.x), sp(q.y)); }
    { const float2 q = cs[3]; rx_pk<2>(R, I, sp(q.x), sp(q.y)); }
    { const float2 q = cs[4]; rx_pk<1>(R, I, sp(q.x), sp(q.y)); }
    { const float2 q = cs[5]; rx_pk0(R, I, sp(q.x), sp(q.y)); }
}

// combined diagonal (6 RZs) in packed layout: z[k] = (zx(2k),zx(2k+1),zy(2k),zy(2k+1))
__device__ __forceinline__ void diag_pk(f2* R, f2* I, const float4* __restrict__ z) {
    #pragma unroll
    for (int k = 0; k < 32; ++k) {
        const float4 q = z[k];
        f2 zx; zx.x = q.x; zx.y = q.y;
        f2 zy; zy.x = q.z; zy.y = q.w;
        const f2 nr = R[k] * zx - I[k] * zy;
        const f2 ni = I[k] * zx + R[k] * zy;
        R[k] = nr; I[k] = ni;
    }
}

// compile-time permutation (register renames; pair->pair with optional half-swap)
__device__ __forceinline__ void perm_pk(f2* R, f2* I) {
    f2 tR[32], tI[32];
    #pragma unroll
    for (int k = 0; k < 32; ++k) {
        const int s0 = perm64c(2 * k);
        const int k2 = s0 >> 1;
        if (s0 & 1) { tR[k] = R[k2].yx; tI[k] = I[k2].yx; }
        else        { tR[k] = R[k2];    tI[k] = I[k2];    }
    }
    #pragma unroll
    for (int k = 0; k < 32; ++k) { R[k] = tR[k]; I[k] = tI[k]; }
}

// CNOT(5,6) in L2 layout: wire5 = packed-internal bit, wire6 = lane bit5
__device__ __forceinline__ void cnot56_L2(f2* R, f2* I) {
    #pragma unroll
    for (int k = 0; k < 32; ++k) {
        R[k].y = __shfl_xor(R[k].y, 32, 64);
        I[k].y = __shfl_xor(I[k].y, 32, 64);
    }
}

// CNOT(5,6) in L1 layout: wire5 = lane bit0, wire6 = packed-index bit4
__device__ __forceinline__ void cnot56_L1(f2* R, f2* I, int lane) {
    const bool c = (lane & 1) != 0;
    #pragma unroll
    for (int k = 0; k < 16; ++k) {
        const f2 a0 = R[k], a1 = R[k + 16], b0 = I[k], b1 = I[k + 16];
        R[k]      = c ? a1 : a0;  R[k + 16] = c ? a0 : a1;
        I[k]      = c ? b1 : b0;  I[k + 16] = c ? b0 : b1;
    }
}

// ---------------- in-wave 64x64 transpose via LDS (no barriers) ----------------
// logical (row R, col C) stored at byte R*256 + (((C>>2) ^ (R&15))<<4) + (C&3)*4
// read addr for row r, col=lane: rb ^ (((r&15)<<4) | (r<<8)),
// rb = ((lane>>2)<<4) | ((lane&3)<<2)
template<bool PRE, bool POST>
__device__ __forceinline__ void tpose(float* pl, f2* R, f2* I, const int lane, const int rb) {
    char* base = reinterpret_cast<char*>(pl);
    const int ls = lane & 15;
    const int wb = lane << 8;
    // ---- RE plane ----
    #pragma unroll
    for (int g = 0; g < 16; ++g) {
        float4 v;
        v.x = elv(R, PRE ? perm64c(4 * g + 0) : 4 * g + 0);
        v.y = elv(R, PRE ? perm64c(4 * g + 1) : 4 * g + 1);
        v.z = elv(R, PRE ? perm64c(4 * g + 2) : 4 * g + 2);
        v.w = elv(R, PRE ? perm64c(4 * g + 3) : 4 * g + 3);
        *reinterpret_cast<float4*>(base + wb + ((g ^ ls) << 4)) = v;
    }
    #pragma unroll
    for (int k = 0; k < 32; ++k) {
        const int r0 = POST ? perm64c(2 * k) : 2 * k;
        const int r1 = r0 ^ 1;               // perm64c(2k+1) == perm64c(2k)^1
        f2 nv;
        nv.x = *reinterpret_cast<const float*>(base + (rb ^ (((r0 & 15) << 4) | (r0 << 8))));
        nv.y = *reinterpret_cast<const float*>(base + (rb ^ (((r1 & 15) << 4) | (r1 << 8))));
        R[k] = nv;
    }
    // ---- IM plane (reuses buffer; per-wave DS ordering guarantees WAR safety) ----
    #pragma unroll
    for (int g = 0; g < 16; ++g) {
        float4 v;
        v.x = elv(I, PRE ? perm64c(4 * g + 0) : 4 * g + 0);
        v.y = elv(I, PRE ? perm64c(4 * g + 1) : 4 * g + 1);
        v.z = elv(I, PRE ? perm64c(4 * g + 2) : 4 * g + 2);
        v.w = elv(I, PRE ? perm64c(4 * g + 3) : 4 * g + 3);
        *reinterpret_cast<float4*>(base + wb + ((g ^ ls) << 4)) = v;
    }
    #pragma unroll
    for (int k = 0; k < 32; ++k) {
        const int r0 = POST ? perm64c(2 * k) : 2 * k;
        const int r1 = r0 ^ 1;
        f2 nv;
        nv.x = *reinterpret_cast<const float*>(base + (rb ^ (((r0 & 15) << 4) | (r0 << 8))));
        nv.y = *reinterpret_cast<const float*>(base + (rb ^ (((r1 & 15) << 4) | (r1 << 8))));
        I[k] = nv;
    }
}

// ---------------- precompute (batch-uniform gate constants) ----------------
__global__ void qr_pre(const float* __restrict__ params,
                       float2* __restrict__ tabcs,   // [8][6]
                       float* __restrict__ zpk)      // [6][32][4] = (zx0,zx1,zy0,zy1)
{
    const int t = threadIdx.x;
    if (t < 48) {
        const int h = t / 6, k = t - h * 6;
        const int l = h >> 1;
        const int base = (((h & 3) == 0) || ((h & 3) == 3)) ? 6 : 0;
        const float th = 0.5f * params[l * 12 + base + k];
        tabcs[t] = make_float2(cosf(th), sinf(th));
    }
    if (t < 384) {
        const int h = t >> 6, j = t & 63;
        const int l = h >> 1;
        const int base = (((h & 3) == 0) || ((h & 3) == 3)) ? 6 : 0;
        float pr = 1.f, pi = 0.f;
        for (int k = 0; k < 6; ++k) {
            const float th = 0.5f * params[l * 12 + base + k];
            const float c = cosf(th), s = sinf(th);
            const float ss = (j & (32 >> k)) ? s : -s;   // bit set -> e^{+i th/2}
            const float nr = pr * c - pi * ss;
            pi = pr * ss + pi * c;
            pr = nr;
        }
        float* q = zpk + (h * 32 + (j >> 1)) * 4;
        q[j & 1] = pr;
        q[2 + (j & 1)] = pi;
    }
}

// ---------------- main: persistent waves, 1 wave/block, 8 samples each ----
// Occupancy evidence across r1/r2/r5-r10: resident waves/SIMD = 46% of the
// VGPR-tier cap, regardless of block geometry (tier-256 at VGPR 152 -> cap 2,
// measured 0.92). Hypothesis: workgroup dispatch churn (short ~26us waves)
// keeps CUs half-filled. Test: 2048 persistent blocks (8 waves/CU resident =
// tier cap; LDS 8x16K=128K <= 160K), each grid-striding over 8 samples ->
// block lifetime x8, dispatch pressure /8. Per-sample code identical to r7.
// launch_bounds(64, 1): VGPR cap 512 (r6 lesson: tighter caps demote the
// state array to scratch -> GB-scale HBM traffic).
__global__ __launch_bounds__(64, 1) void qr_main(
    const float* __restrict__ inputs,
    const float2* __restrict__ tabcs,
    const float4* __restrict__ zpk,
    const float* __restrict__ head_w,
    const float* __restrict__ head_b,
    float* __restrict__ out,
    const int batch)
{
    __shared__ __align__(16) float pl[4096];   // 16 KiB transpose buffer
    const int lane = threadIdx.x;

    // transpose read-address base (bytes); per-row constants folded at compile time
    const int rb = (((lane >> 2) << 4) | ((lane & 3) << 2));

    // sample-invariant measurement constants (hoisted out of the sample loop)
    float w[12];
    #pragma unroll
    for (int i = 0; i < 12; ++i) w[i] = head_w[i];
    const float hb = head_b[0];

    float C = 0.f; int par = 0;
    #pragma unroll
    for (int i = 0; i < 6; ++i) {
        par ^= (lane >> (5 - i)) & 1;
        C += par ? -w[i] : w[i];
    }
    const float sg = par ? -1.f : 1.f;

    #pragma unroll 1
    for (int b = blockIdx.x; b < batch; b += gridDim.x) {
        // per-sample encoding angles
        float cy[12], sy[12];
        #pragma unroll
        for (int i = 0; i < 12; ++i) {
            __sincosf(0.5f * inputs[b * 12 + i], &sy[i], &cy[i]);
        }

        // product-state init in L1 (lane bits = wires 0-5, local bits = wires 6-11)
        float F = 1.f;
        #pragma unroll
        for (int i = 0; i < 6; ++i) F *= (lane & (32 >> i)) ? sy[i] : cy[i];

        float hi[8];
        #pragma unroll
        for (int m = 0; m < 8; ++m)
            hi[m] = ((m & 4) ? sy[6] : cy[6]) * ((m & 2) ? sy[7] : cy[7]) * ((m & 1) ? sy[8] : cy[8]);
        f2 lop[4];
        #pragma unroll
        for (int m = 0; m < 4; ++m) {
            const float q = ((m & 2) ? sy[9] : cy[9]) * ((m & 1) ? sy[10] : cy[10]);
            lop[m].x = q * cy[11];
            lop[m].y = q * sy[11];
        }

        f2 R[32], I[32];
        #pragma unroll
        for (int k = 0; k < 32; ++k) {
            R[k] = sp(F * hi[k >> 2]) * lop[k & 3];
            I[k] = sp(0.f);
        }

        // 8 half-layers; layout alternates L1/L2 via transposes
        #pragma unroll 1
        for (int h = 0; h < 8; ++h) {
            rx_sweep(R, I, tabcs + h * 6);
            if (h < 6) diag_pk(R, I, zpk + h * 32);

            if (h == 1 || h == 5) {
                perm_pk(R, I);           // CNOT(0,1)..(4,5) renames (L2)
                cnot56_L2(R, I);         // CNOT(5,6); chain(6..11) deferred
            } else if (h == 3) {
                cnot56_L1(R, I, lane);   // CNOT(5,6) in L1
                perm_pk(R, I);           // CNOT(6,7)..(10,11) renames (L1)
            } else if (h == 0 || h == 4) {
                tpose<false, false>(pl, R, I, lane, rb);
            } else if (h == 2) {
                tpose<true, true>(pl, R, I, lane, rb);   // pre: this layer's (0,1)..(4,5); post: deferred chain
            } else if (h == 6) {
                tpose<false, true>(pl, R, I, lane, rb);  // post: layer-2's deferred chain
            }
            // h == 7: done (layer-3 RZs + CNOT chain folded into measurement)
        }

        // measurement in L1; layer-3 CNOT chain -> prefix-parity signs
        float phi = 0.f;
        #pragma unroll
        for (int j = 0; j < 64; ++j) {
            const float re = elv(R, j), im = elv(I, j);
            const float p = re * re + im * im;
            float D = 0.f;
            #pragma unroll
            for (int k = 0; k < 6; ++k) {
                D += ppar(j, k) ? -w[6 + k] : w[6 + k];
            }
            phi += (C + sg * D) * p;
        }

        #pragma unroll
        for (int m = 32; m; m >>= 1) phi += __shfl_xor(phi, m, 64);
        if (lane == 0) out[b] = phi + hb;
    }
}

extern "C" void kernel_launch(void* const* d_in, const int* in_sizes, int n_in,
                              void* d_out, int out_size, void* d_ws, size_t ws_size,
                              hipStream_t stream) {
    const float* inputs = (const float*)d_in[0];
    const float* params = (const float*)d_in[1];
    const float* head_w = (const float*)d_in[2];
    const float* head_b = (const float*)d_in[3];
    float* out = (float*)d_out;

    float2* tabcs = (float2*)d_ws;                 // 48 float2 = 384 B
    float*  zpk   = (float*)d_ws + 96;             // 6*32 float4 = 3072 B (16B-aligned: 384%16==0)

    const int batch = in_sizes[0] / NW;

    // 2048 persistent blocks (8 per CU = the VGPR-tier residency cap), each
    // grid-strides over batch/2048 = 8 samples.
    int nblk = 2048;
    if (nblk > batch) nblk = batch;

    qr_pre<<<1, 384, 0, stream>>>(params, tabcs, zpk);
    qr_main<<<nblk, 64, 0, stream>>>(inputs, tabcs, (const float4*)zpk, head_w, head_b, out, batch);
}